// Round 10
// baseline (3362.974 us; speedup 1.0000x reference)
//
#include <hip/hip_runtime.h>
#include <hip/hip_bf16.h>
#include <math.h>

typedef __bf16 bf16;
typedef __bf16 bf16x8 __attribute__((ext_vector_type(8)));
typedef __bf16 bf16x4 __attribute__((ext_vector_type(4)));
typedef float f32x4 __attribute__((ext_vector_type(4)));
typedef unsigned int u32;
typedef u32 u32x4 __attribute__((ext_vector_type(4)));

#define NINP 400
#define HS   1000
#define HP   1024
#define B_   8
#define T_   256
#define NT   2048   /* B_*T_ */
#define M_   4096   /* 4 gates * HP */

#define HT_OFF   819200
#define CT_OFF   827200
#define AUX_OFF  835200

typedef __attribute__((address_space(1))) const void gvoid;
typedef __attribute__((address_space(3))) void lvoid;

__device__ __forceinline__ void async_copy16(void* lds, const void* g) {
  __builtin_amdgcn_global_load_lds((gvoid*)g, (lvoid*)lds, 16, 0, 0);
}

__device__ __forceinline__ float sigm(float x) { return 1.0f / (1.0f + expf(-x)); }

// ---------------- repack kernels (fp32 inputs -> packed-m bf16) ----------------
// M-packing (unchanged): pm = (h>>5)*128 + ((h>>4)&1)*64 + g*16 + (h&15).
// W k-layout: k < K/2 -> tap0 (applied to time-shifted input), k >= K/2 -> tap1.

__global__ void repack_w1(const float* __restrict__ w1, bf16* __restrict__ W1q) {
  int idx = blockIdx.x * 256 + threadIdx.x;           // 4096*1024
  if (idx >= M_ * 1024) return;
  int pm = idx >> 10, k = idx & 1023;
  int g = (pm >> 4) & 3;
  int h = (pm >> 7) * 32 + ((pm >> 6) & 1) * 16 + (pm & 15);
  float v = 0.0f;
  if (h < HS) {
    int c = g * HS + h;
    if (k < 512) { if (k < NINP) v = w1[(size_t)c * (NINP * 2) + k * 2 + 0]; }
    else { int j = k - 512; if (j < NINP) v = w1[(size_t)c * (NINP * 2) + j * 2 + 1]; }
  }
  W1q[idx] = (bf16)v;
}

__global__ void repack_w2(const float* __restrict__ w2, bf16* __restrict__ W2q) {
  int idx = blockIdx.x * 256 + threadIdx.x;           // 4096*2048
  if (idx >= M_ * 2048) return;
  int pm = idx >> 11, k = idx & 2047;
  int g = (pm >> 4) & 3;
  int h = (pm >> 7) * 32 + ((pm >> 6) & 1) * 16 + (pm & 15);
  float v = 0.0f;
  if (h < HS) {
    int c = g * HS + h;
    if (k < HP) { if (k < HS) v = w2[(size_t)c * (HS * 2) + k * 2 + 0]; }
    else { int j = k - HP; if (j < HS) v = w2[(size_t)c * (HS * 2) + j * 2 + 1]; }
  }
  W2q[idx] = (bf16)v;
}

// XSg[(1+n)][k]: row 0 = zeros; row 1+n = X[b][k][t] for n=b*T_+t.
// Read as: tap1 of time-row n  -> XSg[n+1] = X[n]
//          tap0 of time-row n  -> XSg[n]   = X[n-1]  (valid for t>0; t==0 rows
//          must read the ZERO pad -> per-lane pointer select to row 0 [r10 fix:
//          r9 read X[prev batch, t=255] at batch boundaries]).
__global__ void build_xs(const float* __restrict__ X, bf16* __restrict__ XSg) {
  int idx = blockIdx.x * 256 + threadIdx.x;           // (NT+1)*512
  if (idx >= (NT + 1) * 512) return;
  int row = idx >> 9, k = idx & 511;
  float v = 0.0f;
  if (row > 0 && k < NINP) {
    int n = row - 1;
    int b = n >> 8, t = n & (T_ - 1);
    v = X[((size_t)b * NINP + k) * T_ + t];
  }
  XSg[idx] = (bf16)v;
}

__global__ void build_hc(const float* __restrict__ hid, const float* __restrict__ cell,
                         bf16* __restrict__ hidp, float* __restrict__ cellp) {
  int idx = blockIdx.x * 256 + threadIdx.x;           // 8*1024
  if (idx >= B_ * HP) return;
  int b = idx >> 10, k = idx & (HP - 1);
  hidp[idx]  = (k < HS) ? (bf16)hid[b * HS + k] : (bf16)0.0f;
  cellp[idx] = (k < HS) ? cell[b * HS + k] : 0.0f;
}

// ---------------- fused GEMM (+gating), 16x16x32 MFMA, direct-B ----------------
// BM=128 x BN=128, 4 waves (64x64), 2 blocks/CU.  B NEVER TOUCHES LDS: the
// 16x16x32 B-fragment for lane (col,quad) is B[n][k + quad*8 .. +7] -- one
// aligned 16B chunk, loaded directly with global_load_dwordx4 into the MFMA
// operand register.  Deletes half of all LDS reads and a third of DMA writes
// (the measured r5 bottleneck), and the conv tap shift becomes a per-lane base
// pointer (row n-1 vs n; boundary lanes select hidp / the XSg zero guard row
// at init -- divergent pointer VALUES are free for per-lane loads, unlike the
// divergent LDS read that caused r7's 5.6x conflict regression).
// A keeps r5's PROVEN layout: [2][128][64] dbuf, source-rotation swo staging,
// chunk=((kc>>3)+quad+row)&7 reads (229K-conflict level).
// Schedule: ONE vmcnt(0)+barrier per BK=64 tile:
//   top(t):  s_waitcnt vmcnt(0)   <- A(t) DMA + B(t) regs retired (issued t-1)
//            s_barrier            <- A(t) published; LDS[buf^1] free
//            stage A(t+1); load B(t+1) regs   <- 1-iter prefetch (~600cy cover)
//            ph kc=0 / kc=32: 4 ds_read + lgkm + setprio + 16 MFMA each
// K is a template param -> full unroll -> all B offsets immediate, all register
// arrays statically indexed (rule #20).  CbIn (conv1) hoisted to regs.

template <bool GATED, int K>
__global__ __launch_bounds__(256, 2) void gemm_step(
    const bf16* __restrict__ A,      // W2q [4096][2048] or W1q [4096][1024] packed-m
    const bf16* __restrict__ Bsrc,   // gated: Hprev [NT][1024]; plain: XSg [(NT+1)][512]
    const bf16* __restrict__ hidp,   // [B_][HP]
    const bf16* __restrict__ CbIn,   // gated: CbP [NT][4096] packed-m
    bf16* __restrict__ CbOut,        // plain: write CbP
    const float* __restrict__ b2,
    const bf16* __restrict__ ctprev, // [HP][NT]
    const float* __restrict__ cellp, // [B_][HP]
    bf16* __restrict__ ctnew,        // [HP][NT]
    bf16* __restrict__ Hnew) {       // [NT][HP]
  constexpr int KH = K / 2;          // 1024 (gated) or 512 (plain)
  constexpr int BS = KH;             // B row stride
  constexpr int NIT = K / 64;        // 32 or 16 (even)
  __shared__ bf16 As[2][128][64];    // 32 KB

  const int tid = threadIdx.x;
  const int lane = tid & 63;
  const int w = tid >> 6;            // 0..3
  const int mh = w >> 1, nh = w & 1; // wave tile (mh*64, nh*64)
  const int dr = lane >> 3, c8 = lane & 7;
  const int swo = ((c8 - dr) & 7) * 8;     // A staging source rotation (r5)
  const int quad = lane >> 4, col = lane & 15;

  // XCD swizzle over 512 blocks (r0-proven)
  const int L = blockIdx.y * gridDim.x + blockIdx.x;
  const int bm = (L & 7) * 4 + (L >> 7);           // 0..31 (128-pm blocks)
  const int n0 = ((L >> 3) & 15) * 128;

  // ---- gated: step-invariant conv1 contribution -> registers ----
  bf16x4 cb0[4], cb1[4], cb2[4], cb3[4];
  if (GATED) {
#pragma unroll
    for (int nt = 0; nt < 4; ++nt) {
      const int n = n0 + nh * 64 + nt * 16 + col;
      const size_t cb = (size_t)n * 4096 + (size_t)(bm * 128 + mh * 64) + quad * 4;
      cb0[nt] = *(const bf16x4*)&CbIn[cb + 0];
      cb1[nt] = *(const bf16x4*)&CbIn[cb + 16];
      cb2[nt] = *(const bf16x4*)&CbIn[cb + 32];
      cb3[nt] = *(const bf16x4*)&CbIn[cb + 48];
    }
  }

  // ---- A stage source pointers (r5-proven) ----
  const bf16* pa[4];
#pragma unroll
  for (int j = 0; j < 4; ++j)
    pa[j] = A + (size_t)(bm * 128 + j * 32 + w * 8 + dr) * K + swo;

  // ---- B fragment base pointers, per lane: [tap][nt] ----
  const bf16* bvbase[2][4];
#pragma unroll
  for (int nt = 0; nt < 4; ++nt) {
    const int n = n0 + nh * 64 + nt * 16 + col;
    const int t = n & (T_ - 1);
    if (GATED) {
      bvbase[1][nt] = Bsrc + (size_t)n * BS + quad * 8;           // tap1: H[n]
      bvbase[0][nt] = (t == 0) ? (hidp + (size_t)(n >> 8) * HP + quad * 8)
                               : (Bsrc + (size_t)(n - 1) * BS + quad * 8);
    } else {
      // tap0 of row n = X[n-1] if t>0 else the zero pad (guard row 0).
      // r10 FIX: r9 used XSg[n] unconditionally -> at batch boundaries
      // (t==0, b>0) that's X[prev batch, t=255], not the zero pad.
      bvbase[0][nt] = (t == 0) ? (Bsrc + quad * 8)                // zero guard row
                               : (Bsrc + (size_t)n * BS + quad * 8);
      bvbase[1][nt] = Bsrc + (size_t)(n + 1) * BS + quad * 8;     // XSg[n+1] = X[n]
    }
  }

  f32x4 acc[4][4];
#pragma unroll
  for (int i = 0; i < 4; ++i)
#pragma unroll
    for (int j = 0; j < 4; ++j) acc[i][j] = (f32x4){0.f, 0.f, 0.f, 0.f};

  auto stage = [&](int buf, int it) {              // 4 x 16B gload_lds / thread
#pragma unroll
    for (int j = 0; j < 4; ++j)
      async_copy16(&As[buf][j * 32 + w * 8][0], pa[j] + it * 64);
  };

  auto loadB = [&](bf16x8 (&dst)[2][4], int it) {  // 8 x dwordx4 / thread
    const int tap = (it * 64 >= KH) ? 1 : 0;
    const int koff = it * 64 - tap * KH;
#pragma unroll
    for (int h = 0; h < 2; ++h)
#pragma unroll
      for (int nt = 0; nt < 4; ++nt)
        dst[h][nt] = *(const bf16x8*)(bvbase[tap][nt] + koff + h * 32);
  };

  auto phases = [&](int buf, bf16x8 (&bvv)[2][4]) {
#pragma unroll
    for (int h = 0; h < 2; ++h) {                  // kc = 0, 32
      bf16x8 av[4];
#pragma unroll
      for (int mt = 0; mt < 4; ++mt) {
        const int rA = mh * 64 + mt * 16 + col;
        av[mt] = *(const bf16x8*)&As[buf][rA][((h * 4 + quad + rA) & 7) * 8];
      }
      asm volatile("s_waitcnt lgkmcnt(0)" ::: "memory");
      __builtin_amdgcn_sched_barrier(0);
      __builtin_amdgcn_s_setprio(1);
#pragma unroll
      for (int mt = 0; mt < 4; ++mt)
#pragma unroll
        for (int nt = 0; nt < 4; ++nt)
          acc[mt][nt] = __builtin_amdgcn_mfma_f32_16x16x32_bf16(av[mt], bvv[h][nt], acc[mt][nt], 0, 0, 0);
      __builtin_amdgcn_s_setprio(0);
    }
  };

  bf16x8 bv0[2][4], bv1[2][4];       // named reg double-buffer (static indexing)
  stage(0, 0);
  loadB(bv0, 0);
#pragma unroll
  for (int it = 0; it < NIT; it += 2) {
    // ---- iter it (buf 0, consumes bv0) ----
    asm volatile("s_waitcnt vmcnt(0)" ::: "memory");   // A(it) + B(it) retired
    __builtin_amdgcn_s_barrier();                      // A(it) published; buf1 free
    if (it + 1 < NIT) { stage(1, it + 1); loadB(bv1, it + 1); }
    phases(0, bv0);
    // ---- iter it+1 (buf 1, consumes bv1) ----
    asm volatile("s_waitcnt vmcnt(0)" ::: "memory");
    __builtin_amdgcn_s_barrier();
    if (it + 2 < NIT) { stage(0, it + 2); loadB(bv0, it + 2); }
    phases(1, bv1);
  }
  __syncthreads();                   // drain for epilogue overlay

  if (!GATED) {
    // epilogue: pack C block [128 n][128 pm] via LDS overlay on As (32 KB)
    bf16 (*Csh)[128] = (bf16(*)[128])&As[0][0][0];
#pragma unroll
    for (int mt = 0; mt < 4; ++mt) {        // mt = gate
#pragma unroll
      for (int nt = 0; nt < 4; ++nt) {
        const int nloc = nh * 64 + nt * 16 + col;
        bf16x4 v;
#pragma unroll
        for (int j = 0; j < 4; ++j) {
          const int h = bm * 32 + mh * 16 + quad * 4 + j;
          const float bias = (h < HS) ? b2[mt * HS + h] : 0.0f;
          v[j] = (bf16)(acc[mt][nt][j] + bias);
        }
        *(bf16x4*)&Csh[nloc][mh * 64 + mt * 16 + quad * 4] = v;
      }
    }
    __syncthreads();
#pragma unroll
    for (int i2 = 0; i2 < 8; ++i2) {
      const int idx = i2 * 256 + tid;       // 128 rows x 16 chunks of 16B
      const int rrow = idx >> 4, off = idx & 15;
      *(u32x4*)&CbOut[(size_t)(n0 + rrow) * 4096 + bm * 128 + off * 8] =
          *(const u32x4*)&Csh[rrow][off * 8];
    }
  } else {
    bf16 (*Hsh)[32] = (bf16(*)[32])&As[0][0][0];   // [128 n][32 h] = 8 KB
#pragma unroll
    for (int nt = 0; nt < 4; ++nt) {
      const int nloc = nh * 64 + nt * 16 + col;
      const int n = n0 + nloc;
      const int b = n >> 8;
      const int t = n & (T_ - 1);
      bf16x4 hv;
#pragma unroll
      for (int j = 0; j < 4; ++j) {
        const int h = bm * 32 + mh * 16 + quad * 4 + j;
        const float ci = acc[0][nt][j] + (float)cb0[nt][j];
        const float co = acc[1][nt][j] + (float)cb1[nt][j];
        const float cg = acc[2][nt][j] + (float)cb2[nt][j];
        const float cf = acc[3][nt][j] + (float)cb3[nt][j];
        const float ctold = (t == 0) ? cellp[b * HP + h]
                                     : (float)ctprev[(size_t)h * NT + (n - 1)];
        const float cn = sigm(cf) * ctold + sigm(ci) * tanhf(cg);
        ctnew[(size_t)h * NT + n] = (bf16)cn;
        hv[j] = (bf16)(sigm(co) * tanhf(cn));
      }
      *(bf16x4*)&Hsh[nloc][mh * 16 + quad * 4] = hv;
    }
    __syncthreads();
#pragma unroll
    for (int i2 = 0; i2 < 2; ++i2) {
      const int idx = i2 * 256 + tid;       // 128 rows x 4 chunks of 16B
      const int rrow = idx >> 2, off = idx & 3;
      *(u32x4*)&Hnew[(size_t)(n0 + rrow) * HP + bm * 32 + off * 8] =
          *(const u32x4*)&Hsh[rrow][off * 8];
    }
  }
}

// ---------------- output kernels (fp32 out) ----------------

__global__ void aux_kernel(const bf16* __restrict__ H, float* __restrict__ out, int s) {
  int idx = blockIdx.x * 256 + threadIdx.x;  // 8*256*100
  if (idx >= NT * 100) return;
  int n = idx / 100;
  int o = (idx % 100) * 4;
  int b = n >> 8, t = n & (T_ - 1);
  bf16x4 v = *(const bf16x4*)&H[(size_t)n * HP + 600 + o];
  f32x4 f = {(float)v[0], (float)v[1], (float)v[2], (float)v[3]};
  *(f32x4*)&out[AUX_OFF + ((size_t)((b * 2 + s) * T_ + t)) * 400 + o] = f;
}

__global__ void final_kernel(const bf16* __restrict__ H, const bf16* __restrict__ ct,
                             float* __restrict__ out) {
  int idx = blockIdx.x * 256 + threadIdx.x;
  if (idx < NT * 100) {
    int n = idx / 100;
    int o = (idx % 100) * 4;
    int b = n >> 8, t = n & (T_ - 1);
    bf16x4 v = *(const bf16x4*)&H[(size_t)n * HP + 600 + o];
    f32x4 f = {(float)v[0], (float)v[1], (float)v[2], (float)v[3]};
    *(f32x4*)&out[(size_t)n * 400 + o] = f;  // out_main [b][t][400]
    *(f32x4*)&out[AUX_OFF + ((size_t)((b * 2 + 1) * T_ + t)) * 400 + o] = f;
  } else {
    int j = idx - NT * 100;
    if (j < 8000) {
      int b = j / 1000, h = j % 1000;
      out[HT_OFF + j] = (float)H[(size_t)(b * T_ + 255) * HP + h];
    } else if (j < 16000) {
      int jj = j - 8000;
      int b = jj / 1000, h = jj % 1000;
      out[CT_OFF + jj] = (float)ct[(size_t)h * NT + b * T_ + 255];
    }
  }
}

// ---------------- launch ----------------

extern "C" void kernel_launch(void* const* d_in, const int* in_sizes, int n_in,
                              void* d_out, int out_size, void* d_ws, size_t ws_size,
                              hipStream_t stream) {
  const float* X    = (const float*)d_in[0];
  const float* hid  = (const float*)d_in[1];
  const float* cell = (const float*)d_in[2];
  const float* w1   = (const float*)d_in[3];
  const float* w2   = (const float*)d_in[4];
  const float* b2   = (const float*)d_in[5];
  float* out = (float*)d_out;

  char* ws = (char*)d_ws;
  size_t off = 0;
  auto alloc = [&](size_t bytes) {
    void* p = ws + off;
    off += (bytes + 255) & ~(size_t)255;
    return p;
  };
  bf16* W2q    = (bf16*)alloc((size_t)M_ * 2048 * 2);   // 16 MB
  bf16* CbP    = (bf16*)alloc((size_t)NT * M_ * 2);     // 16 MB
  bf16* Hb0    = (bf16*)alloc((size_t)NT * HP * 2);     // 4 MB
  bf16* ctb0   = (bf16*)alloc((size_t)HP * NT * 2);     // 4 MB
  bf16* hidp   = (bf16*)alloc((size_t)B_ * HP * 2);
  float* cellp = (float*)alloc((size_t)B_ * HP * 4);
  // Union region: {W1q, XSg} live only until the first GEMM; then {ctb1, Hb1}.
  char* R = (char*)alloc((size_t)12 * 1024 * 1024);     // 12 MB
  bf16* W1q  = (bf16*)R;                                // 8 MB
  bf16* XSg  = (bf16*)(R + (size_t)8 * 1024 * 1024);    // (NT+1)*512*2 = 2.1 MB
  bf16* ctb1 = (bf16*)R;                                // 4 MB
  bf16* Hb1  = (bf16*)(R + (size_t)4 * 1024 * 1024);    // 4 MB

  bf16* Hb[2]  = {Hb0, Hb1};
  bf16* ctb[2] = {ctb0, ctb1};

  hipMemsetAsync(Hb[0], 0, (size_t)NT * HP * 2, stream);
  hipMemsetAsync(ctb[0], 0, (size_t)HP * NT * 2, stream);

  repack_w1<<<(M_ * 1024) / 256, 256, 0, stream>>>(w1, W1q);
  repack_w2<<<(M_ * 2048) / 256, 256, 0, stream>>>(w2, W2q);
  build_xs<<<((NT + 1) * 512) / 256, 256, 0, stream>>>(X, XSg);
  build_hc<<<(B_ * HP) / 256, 256, 0, stream>>>(hid, cell, hidp, cellp);

  dim3 grid(NT / 128, M_ / 128);  // 16 x 32 = 512 blocks, 2/CU (32 KB LDS)
  gemm_step<false, 1024><<<grid, 256, 0, stream>>>(W1q, XSg, nullptr, nullptr, CbP, b2,
                                                   nullptr, nullptr, nullptr, nullptr);
  for (int i = 0; i < 40; ++i) {
    int p = i & 1;
    gemm_step<true, 2048><<<grid, 256, 0, stream>>>(W2q, Hb[p], hidp, CbP, nullptr, nullptr,
                                                    ctb[p], cellp, ctb[p ^ 1], Hb[p ^ 1]);
    if (i == 19) aux_kernel<<<800, 256, 0, stream>>>(Hb[p ^ 1], out, 0);
  }
  final_kernel<<<(NT * 100 + 16000 + 255) / 256, 256, 0, stream>>>(Hb[0], ctb[0], out);
}